// Round 18
// baseline (364.434 us; speedup 1.0000x reference)
//
#include <hip/hip_runtime.h>

#define N_NODES 100000
#define N_EDGES 1600000
#define D_IN 256
#define D_HID 256
#define D_OUT 128
#define SLOTS 64     // max degree capacity; max Poisson(16) deg over 100k ~ 36

#define NB 1024      // buckets
#define NPB 98       // nodes per bucket (98*1024 >= 100000)
#define CAP 2048     // edge capacity per bucket (mean ~1568, +12 sigma)
#define BIN_T 8192   // edges per bin tile
#define BIN_BLKS ((N_EDGES + BIN_T - 1) / BIN_T)        // 196
#define GEMM1_ROWTILES ((N_NODES + 127) / 128)          // 782
#define GEMM1_BLKS (GEMM1_ROWTILES * 2)                 // 1564 (128x128 tiles)
#define FUSE_TILES ((N_NODES + 63) / 64)                // 1563 (64-node tiles)

typedef unsigned int u32;
typedef unsigned short u16;
typedef __attribute__((ext_vector_type(8))) short bf16x8;
typedef __attribute__((ext_vector_type(8))) unsigned short u16x8;
typedef __attribute__((ext_vector_type(4))) float f32x4;

__device__ __forceinline__ u16 f2bf(float v) {
    u32 u = __float_as_uint(v);
    u32 r = (u + 0x7fffu + ((u >> 16) & 1u)) >> 16;   // RNE
    return (u16)r;
}
__device__ __forceinline__ float bf2f(u16 b) {
    return __uint_as_float(((u32)b) << 16);
}

// ---------------------------------------------------------------- K0: weights + gcnt zero
__global__ __launch_bounds__(256) void weights_kernel(
    const float* __restrict__ W1, u16* __restrict__ w1hi,
    const float* __restrict__ W2, u16* __restrict__ w2hi,
    int* __restrict__ gcnt) {
    const int gtid = blockIdx.x * 256 + threadIdx.x;
    const int gstride = gridDim.x * 256;
    for (int i = gtid; i < NB; i += gstride) gcnt[i] = 0;
    for (int i = gtid; i < D_IN * D_HID; i += gstride) {
        const int k = i / D_HID, n = i - k * D_HID;
        w1hi[(size_t)n * D_IN + k] = f2bf(W1[i]);
    }
    for (int i = gtid; i < D_HID * D_OUT; i += gstride) {
        const int k = i / D_OUT, n = i - k * D_OUT;
        w2hi[(size_t)n * D_HID + k] = f2bf(W2[i]);
    }
}

// ---------------------------------------------------------------- gemm1 device tile
// 128x128 tile (bid>>1 = row tile, bid&1 = col tile). A = f32 x staged 128B
// LDS rows (XOR-swizzled 16B chunks), bf16-converted at fragment read;
// B = w1hi 64B rows; bf16 out. smem: 2 x (16KB A + 8KB B) = 48KB.
__device__ __forceinline__ void gemm1_tile(int bid, const float* __restrict__ x,
                                           const u16* __restrict__ B,
                                           u16* __restrict__ Cb, char* smem, int t) {
    const int mBase = (bid >> 1) * 128;
    const int nBase = (bid & 1) * 128;
    constexpr int ABYTES = 16384;
    constexpr int BUF = ABYTES + 8192;
    const int wave = t >> 6;
    const int lane = t & 63;
    const int wm = wave >> 1, wn = wave & 1;
    const int K = D_IN, N = D_HID, M = N_NODES;

    f32x4 acc[4][4];
#pragma unroll
    for (int i = 0; i < 4; ++i)
#pragma unroll
        for (int j = 0; j < 4; ++j) acc[i][j] = (f32x4){0.f, 0.f, 0.f, 0.f};

    const int lr = lane >> 3;
    const int lp = lane & 7;
    const int lc = lp ^ lr;
    const int lr4 = lane >> 2;
    const int lc4 = (lane & 3) ^ (lr4 & 3);

    auto STAGE = [&](int buf, int kt) {
        const int k0 = kt * 32;
        char* ldsbuf = smem + buf * BUF;
        {
            const int coff = k0 + lc * 4;   // f32 elements
#pragma unroll
            for (int q = 0; q < 4; ++q) {
                const int row = wave * 32 + q * 8 + lr;
                int mg = mBase + row;
                if (mg > M - 1) mg = M - 1;
                const float* s = x + (size_t)mg * K + coff;
                char* d = ldsbuf + (wave * 32 + q * 8) * 128;
                __builtin_amdgcn_global_load_lds(
                    (const __attribute__((address_space(1))) u32*)s,
                    (__attribute__((address_space(3))) u32*)d, 16, 0, 0);
            }
        }
        {
            const int coff = k0 + lc4 * 8;
#pragma unroll
            for (int q = 0; q < 2; ++q) {
                const int row = wave * 32 + q * 16 + lr4;
                const int ng = nBase + row;
                const u16* s = B + (size_t)ng * K + coff;
                char* d = ldsbuf + ABYTES + (wave * 32 + q * 16) * 64;
                __builtin_amdgcn_global_load_lds(
                    (const __attribute__((address_space(1))) u32*)s,
                    (__attribute__((address_space(3))) u32*)d, 16, 0, 0);
            }
        }
    };

    auto COMPUTE = [&](int buf) {
        const char* pa = smem + buf * BUF;
        const char* pb = pa + ABYTES;
        const int lm = lane & 15;
        const int c4 = lane >> 4;
        bf16x8 ah[4], bh[4];
#pragma unroll
        for (int i = 0; i < 4; ++i) {
            const int r = wm * 64 + i * 16 + lm;
            const int s = r & 7;
            const f32x4 a0 = *(const f32x4*)(pa + r * 128 + ((2 * c4) ^ s) * 16);
            const f32x4 a1 = *(const f32x4*)(pa + r * 128 + ((2 * c4 + 1) ^ s) * 16);
            bf16x8 h;
#pragma unroll
            for (int j = 0; j < 4; ++j)
                h[j] = (short)((__float_as_uint(a0[j]) + 0x8000u) >> 16);
#pragma unroll
            for (int j = 0; j < 4; ++j)
                h[4 + j] = (short)((__float_as_uint(a1[j]) + 0x8000u) >> 16);
            ah[i] = h;
        }
#pragma unroll
        for (int j = 0; j < 4; ++j) {
            const int r = wn * 64 + j * 16 + lm;
            bh[j] = *(const bf16x8*)(pb + r * 64 + (c4 ^ (r & 3)) * 16);
        }
#pragma unroll
        for (int i = 0; i < 4; ++i)
#pragma unroll
            for (int j = 0; j < 4; ++j)
                acc[i][j] = __builtin_amdgcn_mfma_f32_16x16x32_bf16(ah[i], bh[j], acc[i][j], 0, 0, 0);
    };

    const int NT = K / 32;
    STAGE(0, 0);
#pragma unroll 1
    for (int kt = 0; kt < NT; ++kt) {
        __syncthreads();
        if (kt + 1 < NT) STAGE((kt + 1) & 1, kt + 1);
        COMPUTE(kt & 1);
        __syncthreads();
    }

    const int lm = lane & 15;
    const int c4 = lane >> 4;
#pragma unroll
    for (int i = 0; i < 4; ++i) {
#pragma unroll
        for (int r = 0; r < 4; ++r) {
            const int row = mBase + wm * 64 + i * 16 + c4 * 4 + r;
            if (row < M) {
#pragma unroll
                for (int j = 0; j < 4; ++j) {
                    const int col = nBase + wn * 64 + j * 16 + lm;
                    Cb[(size_t)row * N + col] = f2bf(acc[i][j][r]);
                }
            }
        }
    }
}

// ---------------------------------------------------------------- K1: bin ∥ gemm1 (all tiles)
__global__ __launch_bounds__(256) void fused_bin_gemm1(
    const int* __restrict__ src, const int* __restrict__ dst,
    int* __restrict__ gcnt, int* __restrict__ binned,
    const float* __restrict__ x, const u16* __restrict__ B,
    u16* __restrict__ Cb) {
    __shared__ char smem[49152];
    const int t = threadIdx.x;

    if (blockIdx.x < BIN_BLKS) {
        int* hist = (int*)smem;
        int* cur = hist + NB;
        const int base = blockIdx.x * BIN_T;
#pragma unroll
        for (int q = 0; q < NB / 256; ++q) hist[q * 256 + t] = 0;
        __syncthreads();
#pragma unroll 4
        for (int j = 0; j < BIN_T / 256; ++j) {
            const int e = base + j * 256 + t;
            if (e < N_EDGES) atomicAdd(&hist[dst[e] / NPB], 1);
        }
        __syncthreads();
#pragma unroll
        for (int q = 0; q < NB / 256; ++q) {
            const int b = q * 256 + t;
            const int c = hist[b];
            cur[b] = c ? atomicAdd(&gcnt[b], c) : 0;
        }
        __syncthreads();
#pragma unroll 4
        for (int j = 0; j < BIN_T / 256; ++j) {
            const int e = base + j * 256 + t;
            if (e < N_EDGES) {
                const int d = dst[e];
                const int b = d / NPB;
                const int ld = d - b * NPB;
                const int r = atomicAdd(&cur[b], 1);
                if (r < CAP) binned[(size_t)b * CAP + r] = (ld << 17) | src[e];
            }
        }
        return;
    }
    gemm1_tile(blockIdx.x - BIN_BLKS, x, B, Cb, smem, t);
}

// ---------------------------------------------------------------- K2: bucket scatter
__global__ __launch_bounds__(256) void bucket_scatter(const int* __restrict__ gcnt,
                                                      const int* __restrict__ binned,
                                                      int* __restrict__ deg,
                                                      int* __restrict__ slot,
                                                      float* __restrict__ dinv) {
    __shared__ int degw[NPB];
    __shared__ int slotw[NPB * SLOTS];   // 25,088 B
    const int b = blockIdx.x;
    const int t = threadIdx.x;
    const int nbase = b * NPB;
    for (int i = t; i < NPB; i += 256) degw[i] = 0;
    __syncthreads();
    int cnt = gcnt[b];
    if (cnt > CAP) cnt = CAP;
    const int* ep = &binned[(size_t)b * CAP];
    for (int i = t; i < cnt; i += 256) {
        const int v = ep[i];
        const int ld = v >> 17;
        const int s = v & 0x1FFFF;
        const int pos = atomicAdd(&degw[ld], 1);
        if (pos < SLOTS) slotw[ld * SLOTS + pos] = s;
    }
    __syncthreads();
    const int lim = min(NPB, N_NODES - nbase);
    if (lim <= 0) return;
    for (int i = t; i < lim * SLOTS; i += 256)
        slot[(size_t)nbase * SLOTS + i] = slotw[i];
    for (int i = t; i < lim; i += 256) {
        const int dgv = degw[i];
        deg[nbase + i] = dgv;
        dinv[nbase + i] = rsqrtf((float)dgv + 1.0f);
    }
}

// ---------------------------------------------------------------- K3: fused gather1 + gemm2
// One block = 64 nodes. Phase 1: gather agg1 rows (relu+bias+self-loop) into
// LDS A-tile [64][256] bf16, XOR-swizzled 16B chunks (chunk ^= row&7).
// Phase 2: h2[tile] = A @ W2t via MFMA, B double-buffered per 32-k step.
// LDS: A 32KB + B 2x8KB = 48KB -> 3 blocks/CU (24 waves, = standalone gather).
__global__ __launch_bounds__(256) void fused_agg_gemm2(
    const u16* __restrict__ h1, const int* __restrict__ deg,
    const int* __restrict__ slot, const float* __restrict__ dinv,
    const float* __restrict__ b1, const u16* __restrict__ W2t,
    u16* __restrict__ h2) {
    __shared__ char smem[49152];
    char* Al = smem;            // [64] rows x 512B, swizzled
    char* Bl = smem + 32768;    // dbuf 2 x 8192
    const int t = threadIdx.x;
    const int tileBase = blockIdx.x * 64;
    const int wave = t >> 6;
    const int lane = t & 63;
    const int lr4 = lane >> 2;
    const int lc4 = (lane & 3) ^ (lr4 & 3);

    auto STAGEB = [&](int buf, int kt) {
        const int coff = kt * 32 + lc4 * 8;
#pragma unroll
        for (int q = 0; q < 2; ++q) {
            const int row = wave * 32 + q * 16 + lr4;          // n index 0..127
            const u16* s = W2t + (size_t)row * D_HID + coff;
            char* d = Bl + buf * 8192 + (wave * 32 + q * 16) * 64;
            __builtin_amdgcn_global_load_lds(
                (const __attribute__((address_space(1))) u32*)s,
                (__attribute__((address_space(3))) u32*)d, 16, 0, 0);
        }
    };

    STAGEB(0, 0);   // B k-step 0 loads during gather phase

    // ---------------- phase 1: gather 64 nodes ----------------
    const int nlane = t & 31;
    const int ng = t >> 5;
#pragma unroll 1
    for (int pass = 0; pass < 8; ++pass) {
        const int row = pass * 8 + ng;          // 0..63
        const int node = tileBase + row;
        if (node < N_NODES) {
            const float di = dinv[node];
            int dg = deg[node];
            if (dg > SLOTS) dg = SLOTS;
            const int* sp = &slot[(size_t)node * SLOTS];
            const int off = nlane * 8;

            float acc[8];
#pragma unroll
            for (int j = 0; j < 8; ++j) acc[j] = 0.f;

            int k = 0;
            for (; k + 1 < dg; k += 2) {
                const int s0 = sp[k];
                const int s1 = sp[k + 1];
                const float n0 = dinv[s0] * di;
                const float n1 = dinv[s1] * di;
                const u16x8 va = *(const u16x8*)&h1[(size_t)s0 * 256 + off];
                const u16x8 vb = *(const u16x8*)&h1[(size_t)s1 * 256 + off];
#pragma unroll
                for (int j = 0; j < 8; ++j)
                    acc[j] += bf2f(va[j]) * n0 + bf2f(vb[j]) * n1;
            }
            if (k < dg) {
                const int s0 = sp[k];
                const float n0 = dinv[s0] * di;
                const u16x8 va = *(const u16x8*)&h1[(size_t)s0 * 256 + off];
#pragma unroll
                for (int j = 0; j < 8; ++j) acc[j] += bf2f(va[j]) * n0;
            }

            const float sl = di * di;
            const u16x8 hv = *(const u16x8*)&h1[(size_t)node * 256 + off];
            const float4 bv0 = *(const float4*)&b1[off];
            const float4 bv1 = *(const float4*)&b1[off + 4];
            const float bb[8] = {bv0.x, bv0.y, bv0.z, bv0.w, bv1.x, bv1.y, bv1.z, bv1.w};
            u16x8 H;
#pragma unroll
            for (int j = 0; j < 8; ++j)
                H[j] = f2bf(fmaxf(acc[j] + bf2f(hv[j]) * sl + bb[j], 0.f));
            *(u16x8*)&Al[row * 512 + ((nlane ^ (row & 7)) * 16)] = H;
        }
    }

    // ---------------- phase 2: h2 tile = A @ W2t ----------------
    const int wm = wave >> 1, wn = wave & 1;
    f32x4 acc2[2][4];
#pragma unroll
    for (int i = 0; i < 2; ++i)
#pragma unroll
        for (int j = 0; j < 4; ++j) acc2[i][j] = (f32x4){0.f, 0.f, 0.f, 0.f};
    const int lm = lane & 15;
    const int c4 = lane >> 4;

#pragma unroll 1
    for (int kt = 0; kt < 8; ++kt) {
        __syncthreads();                       // A writes + B stage(kt) complete
        if (kt + 1 < 8) STAGEB((kt + 1) & 1, kt + 1);
        const char* pb = Bl + (kt & 1) * 8192;
        bf16x8 ah[2], bh[4];
#pragma unroll
        for (int i = 0; i < 2; ++i) {
            const int r = wm * 32 + i * 16 + lm;
            ah[i] = *(const bf16x8*)&Al[r * 512 + (((kt * 4 + c4) ^ (r & 7)) * 16)];
        }
#pragma unroll
        for (int j = 0; j < 4; ++j) {
            const int rn = wn * 64 + j * 16 + lm;
            bh[j] = *(const bf16x8*)(pb + rn * 64 + (c4 ^ (rn & 3)) * 16);
        }
#pragma unroll
        for (int i = 0; i < 2; ++i)
#pragma unroll
            for (int j = 0; j < 4; ++j)
                acc2[i][j] = __builtin_amdgcn_mfma_f32_16x16x32_bf16(ah[i], bh[j], acc2[i][j], 0, 0, 0);
        __syncthreads();
    }

#pragma unroll
    for (int i = 0; i < 2; ++i) {
#pragma unroll
        for (int r = 0; r < 4; ++r) {
            const int row = tileBase + wm * 32 + i * 16 + c4 * 4 + r;
            if (row < N_NODES) {
#pragma unroll
                for (int j = 0; j < 4; ++j) {
                    const int col = wn * 64 + j * 16 + lm;
                    h2[(size_t)row * D_OUT + col] = f2bf(acc2[i][j][r]);
                }
            }
        }
    }
}

// ---------------------------------------------------------------- K4: gather2
// h2 bf16 [N][128]. 16 lanes/node (4 nodes/wave), ushort8/lane; f32 out.
__global__ __launch_bounds__(256) void gather_agg_out(const u16* __restrict__ h,
                                                      const int* __restrict__ deg,
                                                      const int* __restrict__ slot,
                                                      const float* __restrict__ dinv,
                                                      const float* __restrict__ bias,
                                                      float* __restrict__ outp, int n) {
    const int node = blockIdx.x * 16 + (threadIdx.x >> 4);
    const int lane = threadIdx.x & 15;
    if (node >= n) return;
    const float di = dinv[node];
    int dg = deg[node];
    if (dg > SLOTS) dg = SLOTS;
    const int* sp = &slot[(size_t)node * SLOTS];
    const int off = lane * 8;

    float acc[8];
#pragma unroll
    for (int j = 0; j < 8; ++j) acc[j] = 0.f;

    int k = 0;
    for (; k + 1 < dg; k += 2) {
        const int s0 = sp[k];
        const int s1 = sp[k + 1];
        const float n0 = dinv[s0] * di;
        const float n1 = dinv[s1] * di;
        const u16x8 va = *(const u16x8*)&h[(size_t)s0 * 128 + off];
        const u16x8 vb = *(const u16x8*)&h[(size_t)s1 * 128 + off];
#pragma unroll
        for (int j = 0; j < 8; ++j)
            acc[j] += bf2f(va[j]) * n0 + bf2f(vb[j]) * n1;
    }
    if (k < dg) {
        const int s0 = sp[k];
        const float n0 = dinv[s0] * di;
        const u16x8 va = *(const u16x8*)&h[(size_t)s0 * 128 + off];
#pragma unroll
        for (int j = 0; j < 8; ++j) acc[j] += bf2f(va[j]) * n0;
    }

    const float sl = di * di;
    const u16x8 hv = *(const u16x8*)&h[(size_t)node * 128 + off];
    const float4 bv0 = *(const float4*)&bias[off];
    const float4 bv1 = *(const float4*)&bias[off + 4];
    const float bb[8] = {bv0.x, bv0.y, bv0.z, bv0.w, bv1.x, bv1.y, bv1.z, bv1.w};
    float o[8];
#pragma unroll
    for (int j = 0; j < 8; ++j) o[j] = acc[j] + bf2f(hv[j]) * sl + bb[j];
    float4 o0 = make_float4(o[0], o[1], o[2], o[3]);
    float4 o1 = make_float4(o[4], o[5], o[6], o[7]);
    *(float4*)&outp[(size_t)node * 128 + off] = o0;
    *(float4*)&outp[(size_t)node * 128 + off + 4] = o1;
}

// ---------------------------------------------------------------- launch
extern "C" void kernel_launch(void* const* d_in, const int* in_sizes, int n_in,
                              void* d_out, int out_size, void* d_ws, size_t ws_size,
                              hipStream_t stream) {
    const float* x  = (const float*)d_in[0];
    const int*   ei = (const int*)d_in[1];
    const float* W1 = (const float*)d_in[2];
    const float* b1 = (const float*)d_in[3];
    const float* W2 = (const float*)d_in[4];
    const float* b2 = (const float*)d_in[5];
    float* out = (float*)d_out;

    const int* src = ei;
    const int* dst = ei + N_EDGES;

    char* ws = (char*)d_ws;
    float* dinv = (float*)(ws + 0x000000);     // 400 KB
    int*   deg  = (int*)  (ws + 0x080000);     // 400 KB
    int*   gcnt = (int*)  (ws + 0x100000);     // 4 KB
    u16* wt1hi = (u16*)(ws + 0x200000);        // 128 KB
    u16* wt2hi = (u16*)(ws + 0x240000);        // 64 KB
    int* binned = (int*)(ws + 0x280000);       // 8.39 MB -> ends 0xA80000
    int* slot   = (int*)(ws + 0xB00000);       // 25.6 MB -> ends ~0x2440000
    const size_t big = 0x2500000;              // 38.8 MB
    u16* Hb = (u16*)(ws + big);                     // h1 bf16 (51.2 MB)
    u16* H2 = (u16*)(ws + big + 51200000);          // h2 bf16 (25.6 MB)

    // K0: weight hi splits + gcnt zero
    weights_kernel<<<96, 256, 0, stream>>>(W1, wt1hi, W2, wt2hi, gcnt);

    // K1: bin ∥ gemm1 (all 1564 tiles; independent, joins at K3)
    fused_bin_gemm1<<<BIN_BLKS + GEMM1_BLKS, 256, 0, stream>>>(
        src, dst, gcnt, binned, x, wt1hi, Hb);

    // K2: bucket scatter -> slot/deg/dinv
    bucket_scatter<<<NB, 256, 0, stream>>>(gcnt, binned, deg, slot, dinv);

    // K3: fused agg1-gather + gemm2 -> h2 (agg1 never hits global)
    fused_agg_gemm2<<<FUSE_TILES, 256, 0, stream>>>(
        Hb, deg, slot, dinv, b1, wt2hi, H2);

    // K4: out = gather(h2) + h2*dinv^2 + b2
    gather_agg_out<<<(N_NODES + 15) / 16, 256, 0, stream>>>(
        H2, deg, slot, dinv, b2, out, N_NODES);
}

// Round 19
// 303.215 us; speedup vs baseline: 1.2019x; 1.2019x over previous
//
#include <hip/hip_runtime.h>

#define N_NODES 100000
#define N_EDGES 1600000
#define D_IN 256
#define D_HID 256
#define D_OUT 128
#define SLOTS 64     // max degree capacity; max Poisson(16) deg over 100k ~ 36

#define NB 1024      // buckets
#define NPB 98       // nodes per bucket (98*1024 >= 100000)
#define CAP 2048     // edge capacity per bucket (mean ~1568, +12 sigma)
#define BIN_T 8192   // edges per bin tile
#define BIN_BLKS ((N_EDGES + BIN_T - 1) / BIN_T)        // 196
#define GEMM1_ROWTILES ((N_NODES + 127) / 128)          // 782
#define GEMM1_BLKS (GEMM1_ROWTILES * 2)                 // 1564 (128x128 tiles)

typedef unsigned int u32;
typedef unsigned short u16;
typedef __attribute__((ext_vector_type(8))) short bf16x8;
typedef __attribute__((ext_vector_type(8))) unsigned short u16x8;
typedef __attribute__((ext_vector_type(4))) float f32x4;

__device__ __forceinline__ u16 f2bf(float v) {
    u32 u = __float_as_uint(v);
    u32 r = (u + 0x7fffu + ((u >> 16) & 1u)) >> 16;   // RNE
    return (u16)r;
}
__device__ __forceinline__ float bf2f(u16 b) {
    return __uint_as_float(((u32)b) << 16);
}

// ---------------------------------------------------------------- K0: weights + gcnt zero
__global__ __launch_bounds__(256) void weights_kernel(
    const float* __restrict__ W1, u16* __restrict__ w1hi,
    const float* __restrict__ W2, u16* __restrict__ w2hi,
    int* __restrict__ gcnt) {
    const int gtid = blockIdx.x * 256 + threadIdx.x;
    const int gstride = gridDim.x * 256;
    for (int i = gtid; i < NB; i += gstride) gcnt[i] = 0;
    for (int i = gtid; i < D_IN * D_HID; i += gstride) {
        const int k = i / D_HID, n = i - k * D_HID;
        w1hi[(size_t)n * D_IN + k] = f2bf(W1[i]);
    }
    for (int i = gtid; i < D_HID * D_OUT; i += gstride) {
        const int k = i / D_OUT, n = i - k * D_OUT;
        w2hi[(size_t)n * D_HID + k] = f2bf(W2[i]);
    }
}

// ---------------------------------------------------------------- K1: fused bin ∥ gemm1
// blocks [0, BIN_BLKS): edge binning. blocks [BIN_BLKS, ...): gemm1 128x128
// tiles — A = f32 x staged 128B rows, bf16-converted at fragment read;
// B = w1hi 64B rows; bf16 out. Independent work; joins at gather1.
__global__ __launch_bounds__(256) void fused_bin_gemm1(
    const int* __restrict__ src, const int* __restrict__ dst,
    int* __restrict__ gcnt, int* __restrict__ binned,
    const float* __restrict__ x, const u16* __restrict__ B,
    u16* __restrict__ Cb) {
    __shared__ char smem[49152];
    const int t = threadIdx.x;

    if (blockIdx.x < BIN_BLKS) {
        // ---------------- bin branch ----------------
        int* hist = (int*)smem;
        int* cur = hist + NB;
        const int base = blockIdx.x * BIN_T;
#pragma unroll
        for (int q = 0; q < NB / 256; ++q) hist[q * 256 + t] = 0;
        __syncthreads();
#pragma unroll 4
        for (int j = 0; j < BIN_T / 256; ++j) {
            const int e = base + j * 256 + t;
            if (e < N_EDGES) atomicAdd(&hist[dst[e] / NPB], 1);
        }
        __syncthreads();
#pragma unroll
        for (int q = 0; q < NB / 256; ++q) {
            const int b = q * 256 + t;
            const int c = hist[b];
            cur[b] = c ? atomicAdd(&gcnt[b], c) : 0;
        }
        __syncthreads();
#pragma unroll 4
        for (int j = 0; j < BIN_T / 256; ++j) {
            const int e = base + j * 256 + t;
            if (e < N_EDGES) {
                const int d = dst[e];
                const int b = d / NPB;
                const int ld = d - b * NPB;
                const int r = atomicAdd(&cur[b], 1);
                if (r < CAP) binned[(size_t)b * CAP + r] = (ld << 17) | src[e];
            }
        }
        return;
    }

    // ---------------- gemm1 branch ----------------
    const int bid = blockIdx.x - BIN_BLKS;
    const int mBase = (bid >> 1) * 128;
    const int nBase = (bid & 1) * 128;
    constexpr int ABYTES = 16384;          // f32 A: 128 rows x 128B
    constexpr int BUF = ABYTES + 8192;     // + bf16 B: 128 rows x 64B
    const int wave = t >> 6;
    const int lane = t & 63;
    const int wm = wave >> 1, wn = wave & 1;
    const int K = D_IN, N = D_HID, M = N_NODES;

    f32x4 acc[4][4];
#pragma unroll
    for (int i = 0; i < 4; ++i)
#pragma unroll
        for (int j = 0; j < 4; ++j) acc[i][j] = (f32x4){0.f, 0.f, 0.f, 0.f};

    const int lr = lane >> 3;
    const int lp = lane & 7;
    const int lc = lp ^ lr;
    const int lr4 = lane >> 2;
    const int lc4 = (lane & 3) ^ (lr4 & 3);

    auto STAGE = [&](int buf, int kt) {
        const int k0 = kt * 32;
        char* ldsbuf = smem + buf * BUF;
        {
            const int coff = k0 + lc * 4;   // f32 elements
#pragma unroll
            for (int q = 0; q < 4; ++q) {
                const int row = wave * 32 + q * 8 + lr;
                int mg = mBase + row;
                if (mg > M - 1) mg = M - 1;
                const float* s = x + (size_t)mg * K + coff;
                char* d = ldsbuf + (wave * 32 + q * 8) * 128;
                __builtin_amdgcn_global_load_lds(
                    (const __attribute__((address_space(1))) u32*)s,
                    (__attribute__((address_space(3))) u32*)d, 16, 0, 0);
            }
        }
        {
            const int coff = k0 + lc4 * 8;
#pragma unroll
            for (int q = 0; q < 2; ++q) {
                const int row = wave * 32 + q * 16 + lr4;
                const int ng = nBase + row;
                const u16* s = B + (size_t)ng * K + coff;
                char* d = ldsbuf + ABYTES + (wave * 32 + q * 16) * 64;
                __builtin_amdgcn_global_load_lds(
                    (const __attribute__((address_space(1))) u32*)s,
                    (__attribute__((address_space(3))) u32*)d, 16, 0, 0);
            }
        }
    };

    auto COMPUTE = [&](int buf) {
        const char* pa = smem + buf * BUF;
        const char* pb = pa + ABYTES;
        const int lm = lane & 15;
        const int c4 = lane >> 4;
        bf16x8 ah[4], bh[4];
#pragma unroll
        for (int i = 0; i < 4; ++i) {
            const int r = wm * 64 + i * 16 + lm;
            const int s = r & 7;
            const f32x4 a0 = *(const f32x4*)(pa + r * 128 + ((2 * c4) ^ s) * 16);
            const f32x4 a1 = *(const f32x4*)(pa + r * 128 + ((2 * c4 + 1) ^ s) * 16);
            bf16x8 h;
#pragma unroll
            for (int j = 0; j < 4; ++j)
                h[j] = (short)((__float_as_uint(a0[j]) + 0x8000u) >> 16);
#pragma unroll
            for (int j = 0; j < 4; ++j)
                h[4 + j] = (short)((__float_as_uint(a1[j]) + 0x8000u) >> 16);
            ah[i] = h;
        }
#pragma unroll
        for (int j = 0; j < 4; ++j) {
            const int r = wn * 64 + j * 16 + lm;
            bh[j] = *(const bf16x8*)(pb + r * 64 + (c4 ^ (r & 3)) * 16);
        }
#pragma unroll
        for (int i = 0; i < 4; ++i)
#pragma unroll
            for (int j = 0; j < 4; ++j)
                acc[i][j] = __builtin_amdgcn_mfma_f32_16x16x32_bf16(ah[i], bh[j], acc[i][j], 0, 0, 0);
    };

    const int NT = K / 32;
    STAGE(0, 0);
#pragma unroll 1
    for (int kt = 0; kt < NT; ++kt) {
        __syncthreads();
        if (kt + 1 < NT) STAGE((kt + 1) & 1, kt + 1);
        COMPUTE(kt & 1);
        __syncthreads();
    }

    const int lm = lane & 15;
    const int c4 = lane >> 4;
#pragma unroll
    for (int i = 0; i < 4; ++i) {
#pragma unroll
        for (int r = 0; r < 4; ++r) {
            const int row = mBase + wm * 64 + i * 16 + c4 * 4 + r;
            if (row < M) {
#pragma unroll
                for (int j = 0; j < 4; ++j) {
                    const int col = nBase + wn * 64 + j * 16 + lm;
                    Cb[(size_t)row * N + col] = f2bf(acc[i][j][r]);
                }
            }
        }
    }
}

// ---------------------------------------------------------------- K2: bucket scatter
__global__ __launch_bounds__(256) void bucket_scatter(const int* __restrict__ gcnt,
                                                      const int* __restrict__ binned,
                                                      int* __restrict__ deg,
                                                      int* __restrict__ slot,
                                                      float* __restrict__ dinv) {
    __shared__ int degw[NPB];
    __shared__ int slotw[NPB * SLOTS];   // 25,088 B
    const int b = blockIdx.x;
    const int t = threadIdx.x;
    const int nbase = b * NPB;
    for (int i = t; i < NPB; i += 256) degw[i] = 0;
    __syncthreads();
    int cnt = gcnt[b];
    if (cnt > CAP) cnt = CAP;
    const int* ep = &binned[(size_t)b * CAP];
    for (int i = t; i < cnt; i += 256) {
        const int v = ep[i];
        const int ld = v >> 17;
        const int s = v & 0x1FFFF;
        const int pos = atomicAdd(&degw[ld], 1);
        if (pos < SLOTS) slotw[ld * SLOTS + pos] = s;
    }
    __syncthreads();
    const int lim = min(NPB, N_NODES - nbase);
    if (lim <= 0) return;
    for (int i = t; i < lim * SLOTS; i += 256)
        slot[(size_t)nbase * SLOTS + i] = slotw[i];
    for (int i = t; i < lim; i += 256) {
        const int dgv = degw[i];
        deg[nbase + i] = dgv;
        dinv[nbase + i] = rsqrtf((float)dgv + 1.0f);
    }
}

// ---------------------------------------------------------------- K4: gemm2 (bf16 A)
__global__ __launch_bounds__(256) void gemm_bf16(
    const u16* __restrict__ A, const u16* __restrict__ B,
    u16* __restrict__ Cb, int M, int N, int K) {
    constexpr int ABYTES = 8192;
    __shared__ char lds[2][ABYTES + 8192];
    const int t = threadIdx.x;
    const int wave = t >> 6;
    const int lane = t & 63;
    const int wm = wave >> 1, wn = wave & 1;
    const int mBase = blockIdx.y * 128;
    const int nBase = blockIdx.x * 128;

    f32x4 acc[4][4];
#pragma unroll
    for (int i = 0; i < 4; ++i)
#pragma unroll
        for (int j = 0; j < 4; ++j) acc[i][j] = (f32x4){0.f, 0.f, 0.f, 0.f};

    const int lr4 = lane >> 2;
    const int lc4 = (lane & 3) ^ (lr4 & 3);

    auto STAGE = [&](int buf, int kt) {
        const int k0 = kt * 32;
        const int coff = k0 + lc4 * 8;
#pragma unroll
        for (int q = 0; q < 2; ++q) {
            const int row = wave * 32 + q * 16 + lr4;
            int mg = mBase + row;
            if (mg > M - 1) mg = M - 1;
            const u16* s = A + (size_t)mg * K + coff;
            char* d = &lds[buf][(wave * 32 + q * 16) * 64];
            __builtin_amdgcn_global_load_lds(
                (const __attribute__((address_space(1))) u32*)s,
                (__attribute__((address_space(3))) u32*)d, 16, 0, 0);
        }
#pragma unroll
        for (int q = 0; q < 2; ++q) {
            const int row = wave * 32 + q * 16 + lr4;
            const int ng = nBase + row;
            const u16* s = B + (size_t)ng * K + coff;
            char* d = &lds[buf][ABYTES + (wave * 32 + q * 16) * 64];
            __builtin_amdgcn_global_load_lds(
                (const __attribute__((address_space(1))) u32*)s,
                (__attribute__((address_space(3))) u32*)d, 16, 0, 0);
        }
    };

    auto COMPUTE = [&](int buf) {
        const char* pa = &lds[buf][0];
        const char* pb = &lds[buf][ABYTES];
        const int lm = lane & 15;
        const int c4 = lane >> 4;
        bf16x8 ah[4], bh[4];
#pragma unroll
        for (int i = 0; i < 4; ++i) {
            const int r = wm * 64 + i * 16 + lm;
            ah[i] = *(const bf16x8*)(pa + r * 64 + (c4 ^ (r & 3)) * 16);
        }
#pragma unroll
        for (int j = 0; j < 4; ++j) {
            const int r = wn * 64 + j * 16 + lm;
            bh[j] = *(const bf16x8*)(pb + r * 64 + (c4 ^ (r & 3)) * 16);
        }
#pragma unroll
        for (int i = 0; i < 4; ++i)
#pragma unroll
            for (int j = 0; j < 4; ++j)
                acc[i][j] = __builtin_amdgcn_mfma_f32_16x16x32_bf16(ah[i], bh[j], acc[i][j], 0, 0, 0);
    };

    const int NT = K / 32;
    STAGE(0, 0);
#pragma unroll 1
    for (int kt = 0; kt < NT; ++kt) {
        __syncthreads();
        if (kt + 1 < NT) STAGE((kt + 1) & 1, kt + 1);
        COMPUTE(kt & 1);
        __syncthreads();
    }

    const int lm = lane & 15;
    const int c4 = lane >> 4;
#pragma unroll
    for (int i = 0; i < 4; ++i) {
#pragma unroll
        for (int r = 0; r < 4; ++r) {
            const int row = mBase + wm * 64 + i * 16 + c4 * 4 + r;
            if (row < M) {
#pragma unroll
                for (int j = 0; j < 4; ++j) {
                    const int col = nBase + wn * 64 + j * 16 + lm;
                    Cb[(size_t)row * N + col] = f2bf(acc[i][j][r]);
                }
            }
        }
    }
}

// ---------------------------------------------------------------- gathers
// Layer 1: h bf16 [N][256]. 32 lanes/node (2 nodes/wave), ushort8/lane.
__global__ __launch_bounds__(256) void gather_agg_bf16(const u16* __restrict__ h,
                                                       const int* __restrict__ deg,
                                                       const int* __restrict__ slot,
                                                       const float* __restrict__ dinv,
                                                       const float* __restrict__ bias,
                                                       u16* __restrict__ ob, int n) {
    const int node = blockIdx.x * 8 + (threadIdx.x >> 5);
    const int lane = threadIdx.x & 31;
    if (node >= n) return;
    const float di = dinv[node];
    int dg = deg[node];
    if (dg > SLOTS) dg = SLOTS;
    const int* sp = &slot[(size_t)node * SLOTS];
    const int off = lane * 8;

    float acc[8];
#pragma unroll
    for (int j = 0; j < 8; ++j) acc[j] = 0.f;

    int k = 0;
    for (; k + 1 < dg; k += 2) {
        const int s0 = sp[k];
        const int s1 = sp[k + 1];
        const float n0 = dinv[s0] * di;
        const float n1 = dinv[s1] * di;
        const u16x8 va = *(const u16x8*)&h[(size_t)s0 * 256 + off];
        const u16x8 vb = *(const u16x8*)&h[(size_t)s1 * 256 + off];
#pragma unroll
        for (int j = 0; j < 8; ++j)
            acc[j] += bf2f(va[j]) * n0 + bf2f(vb[j]) * n1;
    }
    if (k < dg) {
        const int s0 = sp[k];
        const float n0 = dinv[s0] * di;
        const u16x8 va = *(const u16x8*)&h[(size_t)s0 * 256 + off];
#pragma unroll
        for (int j = 0; j < 8; ++j) acc[j] += bf2f(va[j]) * n0;
    }

    const float sl = di * di;
    const u16x8 hv = *(const u16x8*)&h[(size_t)node * 256 + off];
    const float4 bv0 = *(const float4*)&bias[off];
    const float4 bv1 = *(const float4*)&bias[off + 4];
    const float bb[8] = {bv0.x, bv0.y, bv0.z, bv0.w, bv1.x, bv1.y, bv1.z, bv1.w};
    u16x8 H;
#pragma unroll
    for (int j = 0; j < 8; ++j)
        H[j] = f2bf(fmaxf(acc[j] + bf2f(hv[j]) * sl + bb[j], 0.f));
    *(u16x8*)&ob[(size_t)node * 256 + off] = H;
}

// Layer 2: h bf16 [N][128]. 16 lanes/node (4 nodes/wave), ushort8/lane; f32 out.
__global__ __launch_bounds__(256) void gather_agg_out(const u16* __restrict__ h,
                                                      const int* __restrict__ deg,
                                                      const int* __restrict__ slot,
                                                      const float* __restrict__ dinv,
                                                      const float* __restrict__ bias,
                                                      float* __restrict__ outp, int n) {
    const int node = blockIdx.x * 16 + (threadIdx.x >> 4);
    const int lane = threadIdx.x & 15;
    if (node >= n) return;
    const float di = dinv[node];
    int dg = deg[node];
    if (dg > SLOTS) dg = SLOTS;
    const int* sp = &slot[(size_t)node * SLOTS];
    const int off = lane * 8;

    float acc[8];
#pragma unroll
    for (int j = 0; j < 8; ++j) acc[j] = 0.f;

    int k = 0;
    for (; k + 1 < dg; k += 2) {
        const int s0 = sp[k];
        const int s1 = sp[k + 1];
        const float n0 = dinv[s0] * di;
        const float n1 = dinv[s1] * di;
        const u16x8 va = *(const u16x8*)&h[(size_t)s0 * 128 + off];
        const u16x8 vb = *(const u16x8*)&h[(size_t)s1 * 128 + off];
#pragma unroll
        for (int j = 0; j < 8; ++j)
            acc[j] += bf2f(va[j]) * n0 + bf2f(vb[j]) * n1;
    }
    if (k < dg) {
        const int s0 = sp[k];
        const float n0 = dinv[s0] * di;
        const u16x8 va = *(const u16x8*)&h[(size_t)s0 * 128 + off];
#pragma unroll
        for (int j = 0; j < 8; ++j) acc[j] += bf2f(va[j]) * n0;
    }

    const float sl = di * di;
    const u16x8 hv = *(const u16x8*)&h[(size_t)node * 128 + off];
    const float4 bv0 = *(const float4*)&bias[off];
    const float4 bv1 = *(const float4*)&bias[off + 4];
    const float bb[8] = {bv0.x, bv0.y, bv0.z, bv0.w, bv1.x, bv1.y, bv1.z, bv1.w};
    float o[8];
#pragma unroll
    for (int j = 0; j < 8; ++j) o[j] = acc[j] + bf2f(hv[j]) * sl + bb[j];
    float4 o0 = make_float4(o[0], o[1], o[2], o[3]);
    float4 o1 = make_float4(o[4], o[5], o[6], o[7]);
    *(float4*)&outp[(size_t)node * 128 + off] = o0;
    *(float4*)&outp[(size_t)node * 128 + off + 4] = o1;
}

// ---------------------------------------------------------------- launch
extern "C" void kernel_launch(void* const* d_in, const int* in_sizes, int n_in,
                              void* d_out, int out_size, void* d_ws, size_t ws_size,
                              hipStream_t stream) {
    const float* x  = (const float*)d_in[0];
    const int*   ei = (const int*)d_in[1];
    const float* W1 = (const float*)d_in[2];
    const float* b1 = (const float*)d_in[3];
    const float* W2 = (const float*)d_in[4];
    const float* b2 = (const float*)d_in[5];
    float* out = (float*)d_out;

    const int* src = ei;
    const int* dst = ei + N_EDGES;

    char* ws = (char*)d_ws;
    float* dinv = (float*)(ws + 0x000000);     // 400 KB
    int*   deg  = (int*)  (ws + 0x080000);     // 400 KB
    int*   gcnt = (int*)  (ws + 0x100000);     // 4 KB
    u16* wt1hi = (u16*)(ws + 0x200000);        // 128 KB
    u16* wt2hi = (u16*)(ws + 0x240000);        // 64 KB
    int* binned = (int*)(ws + 0x280000);       // 8.39 MB -> ends 0xA80000
    int* slot   = (int*)(ws + 0xB00000);       // 25.6 MB -> ends ~0x2440000
    const size_t big = 0x2500000;              // 38.8 MB
    u16* Phi = (u16*)(ws + big);                    // agg1 bf16 (51.2 MB)
    u16* Hb  = (u16*)(ws + big + 51200000);         // h1 bf16 (51.2) then h2 bf16 (25.6)

    // K0: weight hi splits + gcnt zero
    weights_kernel<<<96, 256, 0, stream>>>(W1, wt1hi, W2, wt2hi, gcnt);

    // K1: bin ∥ gemm1 (independent; join at gather1)
    fused_bin_gemm1<<<BIN_BLKS + GEMM1_BLKS, 256, 0, stream>>>(
        src, dst, gcnt, binned, x, wt1hi, Hb);

    // K2: bucket scatter -> slot/deg/dinv
    bucket_scatter<<<NB, 256, 0, stream>>>(gcnt, binned, deg, slot, dinv);

    // K3: agg1 = relu(gather(h1) + h1*dinv^2 + b1) -> bf16
    gather_agg_bf16<<<(N_NODES + 7) / 8, 256, 0, stream>>>(
        Hb, deg, slot, dinv, b1, Phi, N_NODES);

    // K4: h2 = agg1 @ W2hi -> bf16
    {
        dim3 g(D_OUT / 128, (N_NODES + 127) / 128);
        gemm_bf16<<<g, 256, 0, stream>>>(Phi, wt2hi, Hb, N_NODES, D_OUT, D_HID);
    }
    // K5: out = gather(h2) + h2*dinv^2 + b2
    gather_agg_out<<<(N_NODES + 15) / 16, 256, 0, stream>>>(
        Hb, deg, slot, dinv, b2, out, N_NODES);
}